// Round 6
// baseline (648.923 us; speedup 1.0000x reference)
//
#include <hip/hip_runtime.h>

// GCN 2-layer, CSR-based, atomic-minimized:
//   hist: ONE u64 atomic per edge packs (count<<40 | fixpoint32(ew))
//   alloc: fused dinv + segment allocation (block scan + 1 atomic/block)
//   reorder: counting-sort placement, packs (src, norm)
//   per layer: register-tiled GEMM (2r x DOUT/16 c per thread, float4 LDS) ->
//              per-node gather aggregate (no atomics)

#define DIN1 128
#define DHID 48
#define DOUT 32
#define MASK40 ((1ull << 40) - 1)

__global__ void hist64_kernel(const int* __restrict__ dst, const float* __restrict__ ew,
                              unsigned long long* __restrict__ packed, int E) {
    int e = blockIdx.x * blockDim.x + threadIdx.x;
    if (e < E) {
        unsigned long long add =
            (1ull << 40) | (unsigned long long)((double)ew[e] * 4294967296.0);
        atomicAdd(&packed[dst[e]], add);
    }
}

// decode packed -> dinv, count; allocate contiguous per-node segment via block scan + gcur
__global__ __launch_bounds__(256) void alloc_kernel(const unsigned long long* __restrict__ packed,
                                                    float* __restrict__ dinv,
                                                    int* __restrict__ row_start,
                                                    int* __restrict__ cursor,
                                                    int* __restrict__ count,
                                                    int* __restrict__ gcur, int n) {
    __shared__ int s[256];
    __shared__ int sbase;
    const int tid = threadIdx.x;
    const int i = blockIdx.x * 256 + tid;
    int c = 0;
    if (i < n) {
        unsigned long long v = packed[i];
        c = (int)(v >> 40);
        float deg = (float)((double)(v & MASK40) * (1.0 / 4294967296.0));
        dinv[i] = rsqrtf(deg + 1.0f);  // +1 self-loop
        count[i] = c;
    }
    s[tid] = c;
    __syncthreads();
    for (int off = 1; off < 256; off <<= 1) {  // Hillis-Steele inclusive scan
        int t = (tid >= off) ? s[tid - off] : 0;
        __syncthreads();
        s[tid] += t;
        __syncthreads();
    }
    if (tid == 255) sbase = atomicAdd(gcur, s[255]);
    __syncthreads();
    if (i < n) {
        int st = sbase + s[tid] - c;
        row_start[i] = st;
        cursor[i] = st;
    }
}

// place edges grouped by dst; pack (src, norm) into int2
__global__ void reorder_kernel(const int* __restrict__ src, const int* __restrict__ dst,
                               const float* __restrict__ ew, const float* __restrict__ dinv,
                               int* __restrict__ cursor, int2* __restrict__ ep, int E) {
    int e = blockIdx.x * blockDim.x + threadIdx.x;
    if (e >= E) return;
    int s = src[e];
    int d = dst[e];
    float nm = dinv[s] * ew[e] * dinv[d];
    int pos = atomicAdd(&cursor[d], 1);
    ep[pos] = make_int2(s, __float_as_int(nm));
}

// Register-tiled GEMM: H[r][c] = sum_k relu?(X[r][k]) * W[k][c]
// Block: 256 threads = 16 row-groups x 16 col-groups; thread = 2 rows x (DOUT_/16) cols.
// X tile row-major [ROWS][DIN_+4]; W tile TRANSPOSED [DOUT_][DIN_+4]; float4 reads along k.
template <int DIN_, int DOUT_, bool RELU_IN>
__global__ __launch_bounds__(256) void gemm_kernel(const float* __restrict__ X,
                                                   const float* __restrict__ W,
                                                   float* __restrict__ H, int n) {
    constexpr int ROWS = 32;
    constexpr int CPT = DOUT_ / 16;     // cols per thread
    constexpr int P4 = DIN_ / 4 + 1;    // row pitch in float4 (pad breaks bank aliasing)
    __shared__ float sX[ROWS * P4 * 4];
    __shared__ float sWt[DOUT_ * P4 * 4];
    const int tid = threadIdx.x;
    const int row0 = blockIdx.x * ROWS;

    // stage W transposed
    const float4* W4 = reinterpret_cast<const float4*>(W);
    for (int i = tid; i < DIN_ * DOUT_ / 4; i += 256) {
        float4 v = W4[i];
        int k = (4 * i) / DOUT_;
        int c = (4 * i) % DOUT_;
        sWt[(c + 0) * P4 * 4 + k] = v.x;
        sWt[(c + 1) * P4 * 4 + k] = v.y;
        sWt[(c + 2) * P4 * 4 + k] = v.z;
        sWt[(c + 3) * P4 * 4 + k] = v.w;
    }
    // stage X (optionally relu'd)
    const float4* X4 = reinterpret_cast<const float4*>(X);
    constexpr int C4 = DIN_ / 4;
    for (int i = tid; i < ROWS * C4; i += 256) {
        int r = i / C4;
        int k4 = i % C4;
        float4 v = make_float4(0.f, 0.f, 0.f, 0.f);
        if (row0 + r < n) v = X4[(size_t)(row0 + r) * C4 + k4];
        if (RELU_IN) {
            v.x = fmaxf(v.x, 0.f); v.y = fmaxf(v.y, 0.f);
            v.z = fmaxf(v.z, 0.f); v.w = fmaxf(v.w, 0.f);
        }
        reinterpret_cast<float4*>(sX)[r * P4 + k4] = v;
    }
    __syncthreads();

    const int cg = tid & 15;
    const int r0 = (tid >> 4) * 2;
    const float4* sX4 = reinterpret_cast<const float4*>(sX);
    const float4* sWt4 = reinterpret_cast<const float4*>(sWt);
    float acc[2][CPT];
#pragma unroll
    for (int ri = 0; ri < 2; ++ri)
#pragma unroll
        for (int j = 0; j < CPT; ++j) acc[ri][j] = 0.0f;

    for (int k4 = 0; k4 < C4; ++k4) {
        float4 xa0 = sX4[(r0 + 0) * P4 + k4];
        float4 xa1 = sX4[(r0 + 1) * P4 + k4];
#pragma unroll
        for (int j = 0; j < CPT; ++j) {
            float4 wb = sWt4[(cg + j * 16) * P4 + k4];
            acc[0][j] = fmaf(xa0.x, wb.x, acc[0][j]);
            acc[0][j] = fmaf(xa0.y, wb.y, acc[0][j]);
            acc[0][j] = fmaf(xa0.z, wb.z, acc[0][j]);
            acc[0][j] = fmaf(xa0.w, wb.w, acc[0][j]);
            acc[1][j] = fmaf(xa1.x, wb.x, acc[1][j]);
            acc[1][j] = fmaf(xa1.y, wb.y, acc[1][j]);
            acc[1][j] = fmaf(xa1.z, wb.z, acc[1][j]);
            acc[1][j] = fmaf(xa1.w, wb.w, acc[1][j]);
        }
    }
#pragma unroll
    for (int ri = 0; ri < 2; ++ri) {
        int r = row0 + r0 + ri;
        if (r < n) {
#pragma unroll
            for (int j = 0; j < CPT; ++j) H[(size_t)r * DOUT_ + cg + j * 16] = acc[ri][j];
        }
    }
}

// out[i][c4] = b + dinv[i]^2*h[i][c4] + sum_{edges->i} norm * h[src][c4]
template <int D>
__global__ __launch_bounds__(256) void aggregate_kernel(const int* __restrict__ row_start,
                                                        const int* __restrict__ count,
                                                        const int2* __restrict__ ep,
                                                        const float* __restrict__ h,
                                                        const float* __restrict__ dinv,
                                                        const float* __restrict__ b,
                                                        float* __restrict__ out, int n) {
    constexpr int C = D / 4;
    int gid = blockIdx.x * blockDim.x + threadIdx.x;
    if (gid >= n * C) return;
    int i = gid / C;
    int c = gid % C;
    const float4* h4 = reinterpret_cast<const float4*>(h);
    float di = dinv[i];
    float sl = di * di;
    float4 acc = h4[(size_t)i * C + c];
    acc.x *= sl; acc.y *= sl; acc.z *= sl; acc.w *= sl;
    int r0 = row_start[i], r1 = r0 + count[i];
    for (int k = r0; k < r1; ++k) {
        int2 p = ep[k];
        float nm = __int_as_float(p.y);
        float4 hv = h4[(size_t)p.x * C + c];
        acc.x = fmaf(nm, hv.x, acc.x);
        acc.y = fmaf(nm, hv.y, acc.y);
        acc.z = fmaf(nm, hv.z, acc.z);
        acc.w = fmaf(nm, hv.w, acc.w);
    }
    float4 bv = reinterpret_cast<const float4*>(b)[c];
    acc.x += bv.x; acc.y += bv.y; acc.z += bv.z; acc.w += bv.w;
    reinterpret_cast<float4*>(out)[(size_t)i * C + c] = acc;
}

extern "C" void kernel_launch(void* const* d_in, const int* in_sizes, int n_in,
                              void* d_out, int out_size, void* d_ws, size_t ws_size,
                              hipStream_t stream) {
    const float* x  = (const float*)d_in[0];
    const int*   ei = (const int*)d_in[1];
    const float* ew = (const float*)d_in[2];
    const float* W1 = (const float*)d_in[3];
    const float* b1 = (const float*)d_in[4];
    const float* W2 = (const float*)d_in[5];
    const float* b2 = (const float*)d_in[6];
    float* out = (float*)d_out;

    const int n = in_sizes[0] / DIN1;   // 100000
    const int E = in_sizes[1] / 2;      // 1600000
    const int* src = ei;
    const int* dst = ei + E;

    // workspace layout (16B-aligned chunks; n*8 and n*4 are multiples of 16)
    char* w = (char*)d_ws;
    unsigned long long* packed = (unsigned long long*)w;  w += (size_t)n * 8;  // zeroed
    int*   gcur      = (int*)w;                           w += 16;             // zeroed
    float* dinv      = (float*)w;                         w += (size_t)n * 4;
    int*   row_start = (int*)w;                           w += (size_t)n * 4;
    int*   cursor    = (int*)w;                           w += (size_t)n * 4;
    int*   count     = (int*)w;                           w += (size_t)n * 4;
    int2*  ep        = (int2*)w;                          w += (size_t)E * 8;
    float* h1        = (float*)w;                         w += (size_t)n * DHID * 4;
    float* out1      = (float*)w;                         w += (size_t)n * DHID * 4;
    float* h2        = (float*)w;

    hipMemsetAsync(packed, 0, (size_t)n * 8 + 16, stream);  // packed + gcur

    hist64_kernel<<<(E + 255) / 256, 256, 0, stream>>>(dst, ew, packed, E);
    alloc_kernel<<<(n + 255) / 256, 256, 0, stream>>>(packed, dinv, row_start, cursor, count,
                                                      gcur, n);
    reorder_kernel<<<(E + 255) / 256, 256, 0, stream>>>(src, dst, ew, dinv, cursor, ep, E);

    // ---- layer 1 ----
    gemm_kernel<DIN1, DHID, false><<<(n + 31) / 32, 256, 0, stream>>>(x, W1, h1, n);
    aggregate_kernel<DHID><<<(n * (DHID / 4) + 255) / 256, 256, 0, stream>>>(
        row_start, count, ep, h1, dinv, b1, out1, n);

    // ---- layer 2 (relu fused into GEMM input load) ----
    gemm_kernel<DHID, DOUT, true><<<(n + 31) / 32, 256, 0, stream>>>(out1, W2, h2, n);
    aggregate_kernel<DOUT><<<(n * (DOUT / 4) + 255) / 256, 256, 0, stream>>>(
        row_start, count, ep, h2, dinv, b2, out, n);
}

// Round 7
// 436.950 us; speedup vs baseline: 1.4851x; 1.4851x over previous
//
#include <hip/hip_runtime.h>

// GCN 2-layer, CSR-based, atomic-minimized:
//   hist: ONE u64 atomic per edge packs (count<<40 | fixpoint32(ew))
//   alloc: fused dinv + segment allocation (block scan + 1 atomic/block)
//   reorder: counting-sort placement, packs (src, norm)
//   per layer: register-tiled GEMM (2r x DOUT/16 c per thread, float4 LDS,
//              unroll-bounded k-loop to avoid spill) ->
//              per-node gather aggregate (no atomics)

#define DIN1 128
#define DHID 48
#define DOUT 32
#define MASK40 ((1ull << 40) - 1)

__global__ void hist64_kernel(const int* __restrict__ dst, const float* __restrict__ ew,
                              unsigned long long* __restrict__ packed, int E) {
    int e = blockIdx.x * blockDim.x + threadIdx.x;
    if (e < E) {
        unsigned long long add =
            (1ull << 40) | (unsigned long long)((double)ew[e] * 4294967296.0);
        atomicAdd(&packed[dst[e]], add);
    }
}

// decode packed -> dinv, count; allocate contiguous per-node segment via block scan + gcur
__global__ __launch_bounds__(256) void alloc_kernel(const unsigned long long* __restrict__ packed,
                                                    float* __restrict__ dinv,
                                                    int* __restrict__ row_start,
                                                    int* __restrict__ cursor,
                                                    int* __restrict__ count,
                                                    int* __restrict__ gcur, int n) {
    __shared__ int s[256];
    __shared__ int sbase;
    const int tid = threadIdx.x;
    const int i = blockIdx.x * 256 + tid;
    int c = 0;
    if (i < n) {
        unsigned long long v = packed[i];
        c = (int)(v >> 40);
        float deg = (float)((double)(v & MASK40) * (1.0 / 4294967296.0));
        dinv[i] = rsqrtf(deg + 1.0f);  // +1 self-loop
        count[i] = c;
    }
    s[tid] = c;
    __syncthreads();
    for (int off = 1; off < 256; off <<= 1) {  // Hillis-Steele inclusive scan
        int t = (tid >= off) ? s[tid - off] : 0;
        __syncthreads();
        s[tid] += t;
        __syncthreads();
    }
    if (tid == 255) sbase = atomicAdd(gcur, s[255]);
    __syncthreads();
    if (i < n) {
        int st = sbase + s[tid] - c;
        row_start[i] = st;
        cursor[i] = st;
    }
}

// place edges grouped by dst; pack (src, norm) into int2
__global__ void reorder_kernel(const int* __restrict__ src, const int* __restrict__ dst,
                               const float* __restrict__ ew, const float* __restrict__ dinv,
                               int* __restrict__ cursor, int2* __restrict__ ep, int E) {
    int e = blockIdx.x * blockDim.x + threadIdx.x;
    if (e >= E) return;
    int s = src[e];
    int d = dst[e];
    float nm = dinv[s] * ew[e] * dinv[d];
    int pos = atomicAdd(&cursor[d], 1);
    ep[pos] = make_int2(s, __float_as_int(nm));
}

// Register-tiled GEMM: H[r][c] = sum_k relu?(X[r][k]) * W[k][c]
// Block: 256 threads = 16 row-groups x 16 col-groups; thread = 2 rows x (DOUT_/16) cols.
// X tile row-major [ROWS][DIN_+4]; W tile TRANSPOSED [DOUT_][DIN_+4]; float4 reads along k.
// k-loop unroll bounded to 4: unbounded unroll spilled (VGPR=256, 474MB scratch writes, r6).
template <int DIN_, int DOUT_, bool RELU_IN>
__global__ __launch_bounds__(256, 4) void gemm_kernel(const float* __restrict__ X,
                                                      const float* __restrict__ W,
                                                      float* __restrict__ H, int n) {
    constexpr int ROWS = 32;
    constexpr int CPT = DOUT_ / 16;     // cols per thread
    constexpr int P4 = DIN_ / 4 + 1;    // row pitch in float4 (pad breaks bank aliasing)
    __shared__ float sX[ROWS * P4 * 4];
    __shared__ float sWt[DOUT_ * P4 * 4];
    const int tid = threadIdx.x;
    const int row0 = blockIdx.x * ROWS;

    // stage W transposed
    const float4* W4 = reinterpret_cast<const float4*>(W);
    for (int i = tid; i < DIN_ * DOUT_ / 4; i += 256) {
        float4 v = W4[i];
        int k = (4 * i) / DOUT_;
        int c = (4 * i) % DOUT_;
        sWt[(c + 0) * P4 * 4 + k] = v.x;
        sWt[(c + 1) * P4 * 4 + k] = v.y;
        sWt[(c + 2) * P4 * 4 + k] = v.z;
        sWt[(c + 3) * P4 * 4 + k] = v.w;
    }
    // stage X (optionally relu'd)
    const float4* X4 = reinterpret_cast<const float4*>(X);
    constexpr int C4 = DIN_ / 4;
    for (int i = tid; i < ROWS * C4; i += 256) {
        int r = i / C4;
        int k4 = i % C4;
        float4 v = make_float4(0.f, 0.f, 0.f, 0.f);
        if (row0 + r < n) v = X4[(size_t)(row0 + r) * C4 + k4];
        if (RELU_IN) {
            v.x = fmaxf(v.x, 0.f); v.y = fmaxf(v.y, 0.f);
            v.z = fmaxf(v.z, 0.f); v.w = fmaxf(v.w, 0.f);
        }
        reinterpret_cast<float4*>(sX)[r * P4 + k4] = v;
    }
    __syncthreads();

    const int cg = tid & 15;
    const int r0 = (tid >> 4) * 2;
    const float4* sX4 = reinterpret_cast<const float4*>(sX);
    const float4* sWt4 = reinterpret_cast<const float4*>(sWt);
    float acc[2][CPT];
#pragma unroll
    for (int ri = 0; ri < 2; ++ri)
#pragma unroll
        for (int j = 0; j < CPT; ++j) acc[ri][j] = 0.0f;

#pragma unroll 4
    for (int k4 = 0; k4 < C4; ++k4) {
        float4 xa0 = sX4[(r0 + 0) * P4 + k4];
        float4 xa1 = sX4[(r0 + 1) * P4 + k4];
#pragma unroll
        for (int j = 0; j < CPT; ++j) {
            float4 wb = sWt4[(cg + j * 16) * P4 + k4];
            acc[0][j] = fmaf(xa0.x, wb.x, acc[0][j]);
            acc[0][j] = fmaf(xa0.y, wb.y, acc[0][j]);
            acc[0][j] = fmaf(xa0.z, wb.z, acc[0][j]);
            acc[0][j] = fmaf(xa0.w, wb.w, acc[0][j]);
            acc[1][j] = fmaf(xa1.x, wb.x, acc[1][j]);
            acc[1][j] = fmaf(xa1.y, wb.y, acc[1][j]);
            acc[1][j] = fmaf(xa1.z, wb.z, acc[1][j]);
            acc[1][j] = fmaf(xa1.w, wb.w, acc[1][j]);
        }
    }
#pragma unroll
    for (int ri = 0; ri < 2; ++ri) {
        int r = row0 + r0 + ri;
        if (r < n) {
#pragma unroll
            for (int j = 0; j < CPT; ++j) H[(size_t)r * DOUT_ + cg + j * 16] = acc[ri][j];
        }
    }
}

// out[i][c4] = b + dinv[i]^2*h[i][c4] + sum_{edges->i} norm * h[src][c4]
template <int D>
__global__ __launch_bounds__(256) void aggregate_kernel(const int* __restrict__ row_start,
                                                        const int* __restrict__ count,
                                                        const int2* __restrict__ ep,
                                                        const float* __restrict__ h,
                                                        const float* __restrict__ dinv,
                                                        const float* __restrict__ b,
                                                        float* __restrict__ out, int n) {
    constexpr int C = D / 4;
    int gid = blockIdx.x * blockDim.x + threadIdx.x;
    if (gid >= n * C) return;
    int i = gid / C;
    int c = gid % C;
    const float4* h4 = reinterpret_cast<const float4*>(h);
    float di = dinv[i];
    float sl = di * di;
    float4 acc = h4[(size_t)i * C + c];
    acc.x *= sl; acc.y *= sl; acc.z *= sl; acc.w *= sl;
    int r0 = row_start[i], r1 = r0 + count[i];
    for (int k = r0; k < r1; ++k) {
        int2 p = ep[k];
        float nm = __int_as_float(p.y);
        float4 hv = h4[(size_t)p.x * C + c];
        acc.x = fmaf(nm, hv.x, acc.x);
        acc.y = fmaf(nm, hv.y, acc.y);
        acc.z = fmaf(nm, hv.z, acc.z);
        acc.w = fmaf(nm, hv.w, acc.w);
    }
    float4 bv = reinterpret_cast<const float4*>(b)[c];
    acc.x += bv.x; acc.y += bv.y; acc.z += bv.z; acc.w += bv.w;
    reinterpret_cast<float4*>(out)[(size_t)i * C + c] = acc;
}

extern "C" void kernel_launch(void* const* d_in, const int* in_sizes, int n_in,
                              void* d_out, int out_size, void* d_ws, size_t ws_size,
                              hipStream_t stream) {
    const float* x  = (const float*)d_in[0];
    const int*   ei = (const int*)d_in[1];
    const float* ew = (const float*)d_in[2];
    const float* W1 = (const float*)d_in[3];
    const float* b1 = (const float*)d_in[4];
    const float* W2 = (const float*)d_in[5];
    const float* b2 = (const float*)d_in[6];
    float* out = (float*)d_out;

    const int n = in_sizes[0] / DIN1;   // 100000
    const int E = in_sizes[1] / 2;      // 1600000
    const int* src = ei;
    const int* dst = ei + E;

    // workspace layout (16B-aligned chunks; n*8 and n*4 are multiples of 16)
    char* w = (char*)d_ws;
    unsigned long long* packed = (unsigned long long*)w;  w += (size_t)n * 8;  // zeroed
    int*   gcur      = (int*)w;                           w += 16;             // zeroed
    float* dinv      = (float*)w;                         w += (size_t)n * 4;
    int*   row_start = (int*)w;                           w += (size_t)n * 4;
    int*   cursor    = (int*)w;                           w += (size_t)n * 4;
    int*   count     = (int*)w;                           w += (size_t)n * 4;
    int2*  ep        = (int2*)w;                          w += (size_t)E * 8;
    float* h1        = (float*)w;                         w += (size_t)n * DHID * 4;
    float* out1      = (float*)w;                         w += (size_t)n * DHID * 4;
    float* h2        = (float*)w;

    hipMemsetAsync(packed, 0, (size_t)n * 8 + 16, stream);  // packed + gcur

    hist64_kernel<<<(E + 255) / 256, 256, 0, stream>>>(dst, ew, packed, E);
    alloc_kernel<<<(n + 255) / 256, 256, 0, stream>>>(packed, dinv, row_start, cursor, count,
                                                      gcur, n);
    reorder_kernel<<<(E + 255) / 256, 256, 0, stream>>>(src, dst, ew, dinv, cursor, ep, E);

    // ---- layer 1 ----
    gemm_kernel<DIN1, DHID, false><<<(n + 31) / 32, 256, 0, stream>>>(x, W1, h1, n);
    aggregate_kernel<DHID><<<(n * (DHID / 4) + 255) / 256, 256, 0, stream>>>(
        row_start, count, ep, h1, dinv, b1, out1, n);

    // ---- layer 2 (relu fused into GEMM input load) ----
    gemm_kernel<DHID, DOUT, true><<<(n + 31) / 32, 256, 0, stream>>>(out1, W2, h2, n);
    aggregate_kernel<DOUT><<<(n * (DOUT / 4) + 255) / 256, 256, 0, stream>>>(
        row_start, count, ep, h2, dinv, b2, out, n);
}

// Round 8
// 349.610 us; speedup vs baseline: 1.8561x; 1.2498x over previous
//
#include <hip/hip_runtime.h>

// GCN 2-layer. Edge pipeline = bucketed counting sort (no far-atomic RMW, no
// partial-line scatter):
//   bin_count:   LDS-privatized per-block histogram over nb=(n+511)>>9 buckets
//   bucket_scan: exclusive scan of bucket counts (1 block)
//   bin_scatter: LDS-stage 2048 edges/block, bucket-group, flush contiguous runs
//   bucket_build:per-bucket two-sweep: LDS count+deg -> scan -> node-grouped ep,
//                writes dinv/row_start/count (deg computed here; no hist pass)
// Per layer: register-tiled GEMM (unroll-bounded, r6 spill lesson) ->
//            per-node gather aggregate, norm computed on the fly (no atomics).

#define DIN1 128
#define DHID 48
#define DOUT 32

// ---------------- edge pipeline ----------------

__global__ __launch_bounds__(256) void bin_count(const int* __restrict__ dst,
                                                 int* __restrict__ bcnt, int E) {
    __shared__ int h[256];
    const int tid = threadIdx.x;
    h[tid] = 0;
    __syncthreads();
    const int base = blockIdx.x * 2048;
#pragma unroll
    for (int j = 0; j < 8; ++j) {
        int e = base + j * 256 + tid;
        if (e < E) atomicAdd(&h[dst[e] >> 9], 1);
    }
    __syncthreads();
    if (h[tid]) atomicAdd(&bcnt[tid], h[tid]);
}

__global__ __launch_bounds__(256) void bucket_scan(const int* __restrict__ bcnt,
                                                   int* __restrict__ bbase,
                                                   int* __restrict__ cursor, int E, int nb) {
    __shared__ int s[256];
    const int tid = threadIdx.x;
    int v = (tid < nb) ? bcnt[tid] : 0;
    s[tid] = v;
    __syncthreads();
    for (int off = 1; off < 256; off <<= 1) {
        int t = (tid >= off) ? s[tid - off] : 0;
        __syncthreads();
        s[tid] += t;
        __syncthreads();
    }
    int excl = s[tid] - v;
    bbase[tid] = excl;
    cursor[tid] = excl;
    if (tid == nb - 1) bbase[nb] = s[tid];  // == E
}

// stage 2048 edges in LDS grouped by bucket, flush contiguous runs per bucket.
// mid entry: x = src | (dst&511)<<17 ; y = ew bits
__global__ __launch_bounds__(256) void bin_scatter(const int* __restrict__ src,
                                                   const int* __restrict__ dst,
                                                   const float* __restrict__ ew,
                                                   int* __restrict__ cursor,
                                                   int2* __restrict__ mid, int E) {
    __shared__ int lcnt[256], loff[256], gbase[256], s[256];
    __shared__ int2 stage[2048];
    __shared__ unsigned char sbk[2048];
    const int tid = threadIdx.x;
    const int base = blockIdx.x * 2048;
    const int cnt = min(2048, E - base);
    lcnt[tid] = 0;
    __syncthreads();
    int myb[8], myr[8];
    int2 mye[8];
#pragma unroll
    for (int j = 0; j < 8; ++j) {
        int e = base + j * 256 + tid;
        myb[j] = -1;
        if (e < E) {
            int d = dst[e];
            int b = d >> 9;
            mye[j] = make_int2(src[e] | ((d & 511) << 17), __float_as_int(ew[e]));
            myr[j] = atomicAdd(&lcnt[b], 1);
            myb[j] = b;
        }
    }
    __syncthreads();
    s[tid] = lcnt[tid];
    __syncthreads();
    for (int off = 1; off < 256; off <<= 1) {
        int t = (tid >= off) ? s[tid - off] : 0;
        __syncthreads();
        s[tid] += t;
        __syncthreads();
    }
    loff[tid] = s[tid] - lcnt[tid];
    if (lcnt[tid] > 0) gbase[tid] = atomicAdd(&cursor[tid], lcnt[tid]);
    __syncthreads();
#pragma unroll
    for (int j = 0; j < 8; ++j) {
        if (myb[j] >= 0) {
            int pos = loff[myb[j]] + myr[j];
            stage[pos] = mye[j];
            sbk[pos] = (unsigned char)myb[j];
        }
    }
    __syncthreads();
    for (int i = tid; i < cnt; i += 256) {
        int b = sbk[i];
        mid[gbase[b] + (i - loff[b])] = stage[i];
    }
}

// one block per bucket: count+deg (LDS atomics), scan, node-grouped scatter into ep
// (64KB L2-local region -> lines merge), write dinv/row_start/count.
__global__ __launch_bounds__(256) void bucket_build(const int2* __restrict__ mid,
                                                    const int* __restrict__ bbase,
                                                    int2* __restrict__ ep,
                                                    float* __restrict__ dinvg,
                                                    int* __restrict__ row_start,
                                                    int* __restrict__ countg, int n) {
    __shared__ float sdeg[512];
    __shared__ int scnt[512], soff[512], scur[512], s2[256];
    const int tid = threadIdx.x;
    const int b = blockIdx.x;
    const int n0 = b << 9;
    const int nr = min(512, n - n0);
    const int e0 = bbase[b], e1 = bbase[b + 1];
    for (int i = tid; i < 512; i += 256) { sdeg[i] = 0.0f; scnt[i] = 0; }
    __syncthreads();
    for (int i = e0 + tid; i < e1; i += 256) {
        int2 p = mid[i];
        int dl = (p.x >> 17) & 511;
        atomicAdd(&scnt[dl], 1);
        atomicAdd(&sdeg[dl], __int_as_float(p.y));
    }
    __syncthreads();
    int a0 = scnt[2 * tid], a1 = scnt[2 * tid + 1];
    s2[tid] = a0 + a1;
    __syncthreads();
    for (int off = 1; off < 256; off <<= 1) {
        int t = (tid >= off) ? s2[tid - off] : 0;
        __syncthreads();
        s2[tid] += t;
        __syncthreads();
    }
    int excl = s2[tid] - (a0 + a1);
    soff[2 * tid] = excl;
    soff[2 * tid + 1] = excl + a0;
    scur[2 * tid] = excl;
    scur[2 * tid + 1] = excl + a0;
    __syncthreads();
    for (int i = tid; i < nr; i += 256) {
        dinvg[n0 + i] = rsqrtf(sdeg[i] + 1.0f);  // +1 self-loop
        row_start[n0 + i] = e0 + soff[i];
        countg[n0 + i] = scnt[i];
    }
    __syncthreads();
    for (int i = e0 + tid; i < e1; i += 256) {
        int2 p = mid[i];
        int dl = (p.x >> 17) & 511;
        int r = atomicAdd(&scur[dl], 1);
        ep[e0 + r] = make_int2(p.x & 0x1FFFF, p.y);
    }
}

// ---------------- dense layers ----------------

// Register-tiled GEMM: H[r][c] = sum_k relu?(X[r][k]) * W[k][c]
// k-loop unroll bounded to 4: unbounded unroll spilled (VGPR=256, 474MB scratch, r6).
template <int DIN_, int DOUT_, bool RELU_IN>
__global__ __launch_bounds__(256, 4) void gemm_kernel(const float* __restrict__ X,
                                                      const float* __restrict__ W,
                                                      float* __restrict__ H, int n) {
    constexpr int ROWS = 32;
    constexpr int CPT = DOUT_ / 16;
    constexpr int P4 = DIN_ / 4 + 1;
    __shared__ float sX[ROWS * P4 * 4];
    __shared__ float sWt[DOUT_ * P4 * 4];
    const int tid = threadIdx.x;
    const int row0 = blockIdx.x * ROWS;

    const float4* W4 = reinterpret_cast<const float4*>(W);
    for (int i = tid; i < DIN_ * DOUT_ / 4; i += 256) {
        float4 v = W4[i];
        int k = (4 * i) / DOUT_;
        int c = (4 * i) % DOUT_;
        sWt[(c + 0) * P4 * 4 + k] = v.x;
        sWt[(c + 1) * P4 * 4 + k] = v.y;
        sWt[(c + 2) * P4 * 4 + k] = v.z;
        sWt[(c + 3) * P4 * 4 + k] = v.w;
    }
    const float4* X4 = reinterpret_cast<const float4*>(X);
    constexpr int C4 = DIN_ / 4;
    for (int i = tid; i < ROWS * C4; i += 256) {
        int r = i / C4;
        int k4 = i % C4;
        float4 v = make_float4(0.f, 0.f, 0.f, 0.f);
        if (row0 + r < n) v = X4[(size_t)(row0 + r) * C4 + k4];
        if (RELU_IN) {
            v.x = fmaxf(v.x, 0.f); v.y = fmaxf(v.y, 0.f);
            v.z = fmaxf(v.z, 0.f); v.w = fmaxf(v.w, 0.f);
        }
        reinterpret_cast<float4*>(sX)[r * P4 + k4] = v;
    }
    __syncthreads();

    const int cg = tid & 15;
    const int r0 = (tid >> 4) * 2;
    const float4* sX4 = reinterpret_cast<const float4*>(sX);
    const float4* sWt4 = reinterpret_cast<const float4*>(sWt);
    float acc[2][CPT];
#pragma unroll
    for (int ri = 0; ri < 2; ++ri)
#pragma unroll
        for (int j = 0; j < CPT; ++j) acc[ri][j] = 0.0f;

#pragma unroll 4
    for (int k4 = 0; k4 < C4; ++k4) {
        float4 xa0 = sX4[(r0 + 0) * P4 + k4];
        float4 xa1 = sX4[(r0 + 1) * P4 + k4];
#pragma unroll
        for (int j = 0; j < CPT; ++j) {
            float4 wb = sWt4[(cg + j * 16) * P4 + k4];
            acc[0][j] = fmaf(xa0.x, wb.x, acc[0][j]);
            acc[0][j] = fmaf(xa0.y, wb.y, acc[0][j]);
            acc[0][j] = fmaf(xa0.z, wb.z, acc[0][j]);
            acc[0][j] = fmaf(xa0.w, wb.w, acc[0][j]);
            acc[1][j] = fmaf(xa1.x, wb.x, acc[1][j]);
            acc[1][j] = fmaf(xa1.y, wb.y, acc[1][j]);
            acc[1][j] = fmaf(xa1.z, wb.z, acc[1][j]);
            acc[1][j] = fmaf(xa1.w, wb.w, acc[1][j]);
        }
    }
#pragma unroll
    for (int ri = 0; ri < 2; ++ri) {
        int r = row0 + r0 + ri;
        if (r < n) {
#pragma unroll
            for (int j = 0; j < CPT; ++j) H[(size_t)r * DOUT_ + cg + j * 16] = acc[ri][j];
        }
    }
}

// out[i][c4] = b + dinv[i]^2*h[i][c4] + sum_{edges->i} dinv[src]*ew*dinv[i] * h[src][c4]
template <int D>
__global__ __launch_bounds__(256) void aggregate_kernel(const int* __restrict__ row_start,
                                                        const int* __restrict__ count,
                                                        const int2* __restrict__ ep,
                                                        const float* __restrict__ h,
                                                        const float* __restrict__ dinv,
                                                        const float* __restrict__ b,
                                                        float* __restrict__ out, int n) {
    constexpr int C = D / 4;
    int gid = blockIdx.x * blockDim.x + threadIdx.x;
    if (gid >= n * C) return;
    int i = gid / C;
    int c = gid % C;
    const float4* h4 = reinterpret_cast<const float4*>(h);
    float di = dinv[i];
    float sl = di * di;
    float4 acc = h4[(size_t)i * C + c];
    acc.x *= sl; acc.y *= sl; acc.z *= sl; acc.w *= sl;
    int r0 = row_start[i], r1 = r0 + count[i];
    for (int k = r0; k < r1; ++k) {
        int2 p = ep[k];
        float nm = dinv[p.x] * __int_as_float(p.y) * di;
        float4 hv = h4[(size_t)p.x * C + c];
        acc.x = fmaf(nm, hv.x, acc.x);
        acc.y = fmaf(nm, hv.y, acc.y);
        acc.z = fmaf(nm, hv.z, acc.z);
        acc.w = fmaf(nm, hv.w, acc.w);
    }
    float4 bv = reinterpret_cast<const float4*>(b)[c];
    acc.x += bv.x; acc.y += bv.y; acc.z += bv.z; acc.w += bv.w;
    reinterpret_cast<float4*>(out)[(size_t)i * C + c] = acc;
}

extern "C" void kernel_launch(void* const* d_in, const int* in_sizes, int n_in,
                              void* d_out, int out_size, void* d_ws, size_t ws_size,
                              hipStream_t stream) {
    const float* x  = (const float*)d_in[0];
    const int*   ei = (const int*)d_in[1];
    const float* ew = (const float*)d_in[2];
    const float* W1 = (const float*)d_in[3];
    const float* b1 = (const float*)d_in[4];
    const float* W2 = (const float*)d_in[5];
    const float* b2 = (const float*)d_in[6];
    float* out = (float*)d_out;

    const int n = in_sizes[0] / DIN1;   // 100000
    const int E = in_sizes[1] / 2;      // 1600000
    const int* src = ei;
    const int* dst = ei + E;
    const int nb = (n + 511) >> 9;      // 196 buckets (<=256)

    // workspace layout (16B-aligned chunks)
    char* w = (char*)d_ws;
    int*   bcnt      = (int*)w;   w += 256 * 4;            // zeroed
    int*   bbase     = (int*)w;   w += 272 * 4;            // nb+1 used
    int*   cursor    = (int*)w;   w += 256 * 4;
    float* dinv      = (float*)w; w += (size_t)n * 4;
    int*   row_start = (int*)w;   w += (size_t)n * 4;
    int*   count     = (int*)w;   w += (size_t)n * 4;
    int2*  mid       = (int2*)w;  w += (size_t)E * 8;
    int2*  ep        = (int2*)w;  w += (size_t)E * 8;
    float* h1        = (float*)w; w += (size_t)n * DHID * 4;
    float* out1      = (float*)w; w += (size_t)n * DHID * 4;
    float* h2        = (float*)w;

    const int eblk = (E + 2047) / 2048;  // 782

    hipMemsetAsync(bcnt, 0, 256 * 4, stream);
    bin_count<<<eblk, 256, 0, stream>>>(dst, bcnt, E);
    bucket_scan<<<1, 256, 0, stream>>>(bcnt, bbase, cursor, E, nb);
    bin_scatter<<<eblk, 256, 0, stream>>>(src, dst, ew, cursor, mid, E);
    bucket_build<<<nb, 256, 0, stream>>>(mid, bbase, ep, dinv, row_start, count, n);

    // ---- layer 1 ----
    gemm_kernel<DIN1, DHID, false><<<(n + 31) / 32, 256, 0, stream>>>(x, W1, h1, n);
    aggregate_kernel<DHID><<<(n * (DHID / 4) + 255) / 256, 256, 0, stream>>>(
        row_start, count, ep, h1, dinv, b1, out1, n);

    // ---- layer 2 (relu fused into GEMM input load) ----
    gemm_kernel<DHID, DOUT, true><<<(n + 31) / 32, 256, 0, stream>>>(out1, W2, h2, n);
    aggregate_kernel<DOUT><<<(n * (DOUT / 4) + 255) / 256, 256, 0, stream>>>(
        row_start, count, ep, h2, dinv, b2, out, n);
}

// Round 9
// 320.568 us; speedup vs baseline: 2.0243x; 1.0906x over previous
//
#include <hip/hip_runtime.h>

// GCN 2-layer. Edge pipeline = bucketed counting sort (no far-atomic RMW, no
// partial-line scatter). h1/h2 stored FP16 (halves random-gather bytes in
// aggregate; rel err 2^-12, well under 4.4e-3 threshold). out1/out stay FP32.
//   bin_count / bucket_scan / bin_scatter / bucket_build: dst-sort + CSR + dinv
//   per layer: register-tiled GEMM (unroll-bounded, r6 spill lesson) -> fp16 h
//              per-node gather aggregate, norm on the fly (no atomics).

#define DIN1 128
#define DHID 48
#define DOUT 32

typedef _Float16 half4_t __attribute__((ext_vector_type(4)));

// ---------------- edge pipeline ----------------

__global__ __launch_bounds__(256) void bin_count(const int* __restrict__ dst,
                                                 int* __restrict__ bcnt, int E) {
    __shared__ int h[256];
    const int tid = threadIdx.x;
    h[tid] = 0;
    __syncthreads();
    const int base = blockIdx.x * 2048;
#pragma unroll
    for (int j = 0; j < 8; ++j) {
        int e = base + j * 256 + tid;
        if (e < E) atomicAdd(&h[dst[e] >> 9], 1);
    }
    __syncthreads();
    if (h[tid]) atomicAdd(&bcnt[tid], h[tid]);
}

__global__ __launch_bounds__(256) void bucket_scan(const int* __restrict__ bcnt,
                                                   int* __restrict__ bbase,
                                                   int* __restrict__ cursor, int E, int nb) {
    __shared__ int s[256];
    const int tid = threadIdx.x;
    int v = (tid < nb) ? bcnt[tid] : 0;
    s[tid] = v;
    __syncthreads();
    for (int off = 1; off < 256; off <<= 1) {
        int t = (tid >= off) ? s[tid - off] : 0;
        __syncthreads();
        s[tid] += t;
        __syncthreads();
    }
    int excl = s[tid] - v;
    bbase[tid] = excl;
    cursor[tid] = excl;
    if (tid == nb - 1) bbase[nb] = s[tid];  // == E
}

// stage 2048 edges in LDS grouped by bucket, flush contiguous runs per bucket.
// mid entry: x = src | (dst&511)<<17 ; y = ew bits
__global__ __launch_bounds__(256) void bin_scatter(const int* __restrict__ src,
                                                   const int* __restrict__ dst,
                                                   const float* __restrict__ ew,
                                                   int* __restrict__ cursor,
                                                   int2* __restrict__ mid, int E) {
    __shared__ int lcnt[256], loff[256], gbase[256], s[256];
    __shared__ int2 stage[2048];
    __shared__ unsigned char sbk[2048];
    const int tid = threadIdx.x;
    const int base = blockIdx.x * 2048;
    const int cnt = min(2048, E - base);
    lcnt[tid] = 0;
    __syncthreads();
    int myb[8], myr[8];
    int2 mye[8];
#pragma unroll
    for (int j = 0; j < 8; ++j) {
        int e = base + j * 256 + tid;
        myb[j] = -1;
        if (e < E) {
            int d = dst[e];
            int b = d >> 9;
            mye[j] = make_int2(src[e] | ((d & 511) << 17), __float_as_int(ew[e]));
            myr[j] = atomicAdd(&lcnt[b], 1);
            myb[j] = b;
        }
    }
    __syncthreads();
    s[tid] = lcnt[tid];
    __syncthreads();
    for (int off = 1; off < 256; off <<= 1) {
        int t = (tid >= off) ? s[tid - off] : 0;
        __syncthreads();
        s[tid] += t;
        __syncthreads();
    }
    loff[tid] = s[tid] - lcnt[tid];
    if (lcnt[tid] > 0) gbase[tid] = atomicAdd(&cursor[tid], lcnt[tid]);
    __syncthreads();
#pragma unroll
    for (int j = 0; j < 8; ++j) {
        if (myb[j] >= 0) {
            int pos = loff[myb[j]] + myr[j];
            stage[pos] = mye[j];
            sbk[pos] = (unsigned char)myb[j];
        }
    }
    __syncthreads();
    for (int i = tid; i < cnt; i += 256) {
        int b = sbk[i];
        mid[gbase[b] + (i - loff[b])] = stage[i];
    }
}

// one block per bucket: count+deg (LDS atomics), scan, node-grouped scatter into ep
// (64KB L2-local region -> lines merge), write dinv/row_start/count.
__global__ __launch_bounds__(256) void bucket_build(const int2* __restrict__ mid,
                                                    const int* __restrict__ bbase,
                                                    int2* __restrict__ ep,
                                                    float* __restrict__ dinvg,
                                                    int* __restrict__ row_start,
                                                    int* __restrict__ countg, int n) {
    __shared__ float sdeg[512];
    __shared__ int scnt[512], soff[512], scur[512], s2[256];
    const int tid = threadIdx.x;
    const int b = blockIdx.x;
    const int n0 = b << 9;
    const int nr = min(512, n - n0);
    const int e0 = bbase[b], e1 = bbase[b + 1];
    for (int i = tid; i < 512; i += 256) { sdeg[i] = 0.0f; scnt[i] = 0; }
    __syncthreads();
    for (int i = e0 + tid; i < e1; i += 256) {
        int2 p = mid[i];
        int dl = (p.x >> 17) & 511;
        atomicAdd(&scnt[dl], 1);
        atomicAdd(&sdeg[dl], __int_as_float(p.y));
    }
    __syncthreads();
    int a0 = scnt[2 * tid], a1 = scnt[2 * tid + 1];
    s2[tid] = a0 + a1;
    __syncthreads();
    for (int off = 1; off < 256; off <<= 1) {
        int t = (tid >= off) ? s2[tid - off] : 0;
        __syncthreads();
        s2[tid] += t;
        __syncthreads();
    }
    int excl = s2[tid] - (a0 + a1);
    soff[2 * tid] = excl;
    soff[2 * tid + 1] = excl + a0;
    scur[2 * tid] = excl;
    scur[2 * tid + 1] = excl + a0;
    __syncthreads();
    for (int i = tid; i < nr; i += 256) {
        dinvg[n0 + i] = rsqrtf(sdeg[i] + 1.0f);  // +1 self-loop
        row_start[n0 + i] = e0 + soff[i];
        countg[n0 + i] = scnt[i];
    }
    __syncthreads();
    for (int i = e0 + tid; i < e1; i += 256) {
        int2 p = mid[i];
        int dl = (p.x >> 17) & 511;
        int r = atomicAdd(&scur[dl], 1);
        ep[e0 + r] = make_int2(p.x & 0x1FFFF, p.y);
    }
}

// ---------------- dense layers ----------------

// Register-tiled GEMM: H[r][c] = (fp16) sum_k relu?(X[r][k]) * W[k][c]
// k-loop unroll bounded to 4: unbounded unroll spilled (VGPR=256, 474MB scratch, r6).
template <int DIN_, int DOUT_, bool RELU_IN>
__global__ __launch_bounds__(256, 4) void gemm_kernel(const float* __restrict__ X,
                                                      const float* __restrict__ W,
                                                      _Float16* __restrict__ H, int n) {
    constexpr int ROWS = 32;
    constexpr int CPT = DOUT_ / 16;
    constexpr int P4 = DIN_ / 4 + 1;
    __shared__ float sX[ROWS * P4 * 4];
    __shared__ float sWt[DOUT_ * P4 * 4];
    const int tid = threadIdx.x;
    const int row0 = blockIdx.x * ROWS;

    const float4* W4 = reinterpret_cast<const float4*>(W);
    for (int i = tid; i < DIN_ * DOUT_ / 4; i += 256) {
        float4 v = W4[i];
        int k = (4 * i) / DOUT_;
        int c = (4 * i) % DOUT_;
        sWt[(c + 0) * P4 * 4 + k] = v.x;
        sWt[(c + 1) * P4 * 4 + k] = v.y;
        sWt[(c + 2) * P4 * 4 + k] = v.z;
        sWt[(c + 3) * P4 * 4 + k] = v.w;
    }
    const float4* X4 = reinterpret_cast<const float4*>(X);
    constexpr int C4 = DIN_ / 4;
    for (int i = tid; i < ROWS * C4; i += 256) {
        int r = i / C4;
        int k4 = i % C4;
        float4 v = make_float4(0.f, 0.f, 0.f, 0.f);
        if (row0 + r < n) v = X4[(size_t)(row0 + r) * C4 + k4];
        if (RELU_IN) {
            v.x = fmaxf(v.x, 0.f); v.y = fmaxf(v.y, 0.f);
            v.z = fmaxf(v.z, 0.f); v.w = fmaxf(v.w, 0.f);
        }
        reinterpret_cast<float4*>(sX)[r * P4 + k4] = v;
    }
    __syncthreads();

    const int cg = tid & 15;
    const int r0 = (tid >> 4) * 2;
    const float4* sX4 = reinterpret_cast<const float4*>(sX);
    const float4* sWt4 = reinterpret_cast<const float4*>(sWt);
    float acc[2][CPT];
#pragma unroll
    for (int ri = 0; ri < 2; ++ri)
#pragma unroll
        for (int j = 0; j < CPT; ++j) acc[ri][j] = 0.0f;

#pragma unroll 4
    for (int k4 = 0; k4 < C4; ++k4) {
        float4 xa0 = sX4[(r0 + 0) * P4 + k4];
        float4 xa1 = sX4[(r0 + 1) * P4 + k4];
#pragma unroll
        for (int j = 0; j < CPT; ++j) {
            float4 wb = sWt4[(cg + j * 16) * P4 + k4];
            acc[0][j] = fmaf(xa0.x, wb.x, acc[0][j]);
            acc[0][j] = fmaf(xa0.y, wb.y, acc[0][j]);
            acc[0][j] = fmaf(xa0.z, wb.z, acc[0][j]);
            acc[0][j] = fmaf(xa0.w, wb.w, acc[0][j]);
            acc[1][j] = fmaf(xa1.x, wb.x, acc[1][j]);
            acc[1][j] = fmaf(xa1.y, wb.y, acc[1][j]);
            acc[1][j] = fmaf(xa1.z, wb.z, acc[1][j]);
            acc[1][j] = fmaf(xa1.w, wb.w, acc[1][j]);
        }
    }
#pragma unroll
    for (int ri = 0; ri < 2; ++ri) {
        int r = row0 + r0 + ri;
        if (r < n) {
#pragma unroll
            for (int j = 0; j < CPT; ++j)
                H[(size_t)r * DOUT_ + cg + j * 16] = (_Float16)acc[ri][j];
        }
    }
}

// out[i][c4] = b + dinv[i]^2*h[i][c4] + sum_{edges->i} dinv[src]*ew*dinv[i] * h[src][c4]
// h is FP16 (halved gather bytes); accumulate FP32.
template <int D>
__global__ __launch_bounds__(256) void aggregate_kernel(const int* __restrict__ row_start,
                                                        const int* __restrict__ count,
                                                        const int2* __restrict__ ep,
                                                        const _Float16* __restrict__ h,
                                                        const float* __restrict__ dinv,
                                                        const float* __restrict__ b,
                                                        float* __restrict__ out, int n) {
    constexpr int C = D / 4;
    int gid = blockIdx.x * blockDim.x + threadIdx.x;
    if (gid >= n * C) return;
    int i = gid / C;
    int c = gid % C;
    const half4_t* h4 = reinterpret_cast<const half4_t*>(h);
    float di = dinv[i];
    float sl = di * di;
    half4_t hs = h4[(size_t)i * C + c];
    float4 acc;
    acc.x = sl * (float)hs[0];
    acc.y = sl * (float)hs[1];
    acc.z = sl * (float)hs[2];
    acc.w = sl * (float)hs[3];
    int r0 = row_start[i], r1 = r0 + count[i];
    for (int k = r0; k < r1; ++k) {
        int2 p = ep[k];
        float nm = dinv[p.x] * __int_as_float(p.y) * di;
        half4_t hv = h4[(size_t)p.x * C + c];
        acc.x = fmaf(nm, (float)hv[0], acc.x);
        acc.y = fmaf(nm, (float)hv[1], acc.y);
        acc.z = fmaf(nm, (float)hv[2], acc.z);
        acc.w = fmaf(nm, (float)hv[3], acc.w);
    }
    float4 bv = reinterpret_cast<const float4*>(b)[c];
    acc.x += bv.x; acc.y += bv.y; acc.z += bv.z; acc.w += bv.w;
    reinterpret_cast<float4*>(out)[(size_t)i * C + c] = acc;
}

extern "C" void kernel_launch(void* const* d_in, const int* in_sizes, int n_in,
                              void* d_out, int out_size, void* d_ws, size_t ws_size,
                              hipStream_t stream) {
    const float* x  = (const float*)d_in[0];
    const int*   ei = (const int*)d_in[1];
    const float* ew = (const float*)d_in[2];
    const float* W1 = (const float*)d_in[3];
    const float* b1 = (const float*)d_in[4];
    const float* W2 = (const float*)d_in[5];
    const float* b2 = (const float*)d_in[6];
    float* out = (float*)d_out;

    const int n = in_sizes[0] / DIN1;   // 100000
    const int E = in_sizes[1] / 2;      // 1600000
    const int* src = ei;
    const int* dst = ei + E;
    const int nb = (n + 511) >> 9;      // 196 buckets (<=256)

    // workspace layout (16B-aligned chunks)
    char* w = (char*)d_ws;
    int*   bcnt      = (int*)w;   w += 256 * 4;            // zeroed
    int*   bbase     = (int*)w;   w += 272 * 4;            // nb+1 used
    int*   cursor    = (int*)w;   w += 256 * 4;
    float* dinv      = (float*)w; w += (size_t)n * 4;
    int*   row_start = (int*)w;   w += (size_t)n * 4;
    int*   count     = (int*)w;   w += (size_t)n * 4;
    int2*  mid       = (int2*)w;  w += (size_t)E * 8;
    int2*  ep        = (int2*)w;  w += (size_t)E * 8;
    _Float16* h1     = (_Float16*)w; w += (size_t)n * DHID * 2;
    float* out1      = (float*)w; w += (size_t)n * DHID * 4;
    _Float16* h2     = (_Float16*)w;

    const int eblk = (E + 2047) / 2048;  // 782

    hipMemsetAsync(bcnt, 0, 256 * 4, stream);
    bin_count<<<eblk, 256, 0, stream>>>(dst, bcnt, E);
    bucket_scan<<<1, 256, 0, stream>>>(bcnt, bbase, cursor, E, nb);
    bin_scatter<<<eblk, 256, 0, stream>>>(src, dst, ew, cursor, mid, E);
    bucket_build<<<nb, 256, 0, stream>>>(mid, bbase, ep, dinv, row_start, count, n);

    // ---- layer 1 ----
    gemm_kernel<DIN1, DHID, false><<<(n + 31) / 32, 256, 0, stream>>>(x, W1, h1, n);
    aggregate_kernel<DHID><<<(n * (DHID / 4) + 255) / 256, 256, 0, stream>>>(
        row_start, count, ep, h1, dinv, b1, out1, n);

    // ---- layer 2 (relu fused into GEMM input load) ----
    gemm_kernel<DHID, DOUT, true><<<(n + 31) / 32, 256, 0, stream>>>(out1, W2, h2, n);
    aggregate_kernel<DOUT><<<(n * (DOUT / 4) + 255) / 256, 256, 0, stream>>>(
        row_start, count, ep, h2, dinv, b2, out, n);
}

// Round 11
// 319.718 us; speedup vs baseline: 2.0297x; 1.0027x over previous
//
#include <hip/hip_runtime.h>

// GCN 2-layer. Bucketed counting-sort edge pipeline + degree-ranked CSR
// (de-diverges aggregate waves) + fp16 h (halved gather bytes) +
// gemm1 grid-fused with bin_scatter (independent -> overlap on one stream).
//   bin_count:    per-block LDS histogram over nb=(n+511)>>9 buckets
//   scatter_gemm1: blocks [0,nsb) = bin_scatter (local bcnt scan, zero-based
//                  cursor); blocks [nsb,..) = register-tiled GEMM1 -> fp16 h1
//   bucket_build: per-bucket: count+deg -> scan -> degree-rank nodes ->
//                 rank-indexed row_start/count/ord + dinv + node-grouped ep
//   aggregate:    per (rank,chunk4): self-loop + bias + gather-accumulate
//   gemm2 / aggregate2: same pattern, relu fused into gemm2 staging.

#define DIN1 128
#define DHID 48
#define DOUT 32

typedef _Float16 half4_t __attribute__((ext_vector_type(4)));

// ---------------- edge pipeline ----------------

__global__ __launch_bounds__(256) void bin_count(const int* __restrict__ dst,
                                                 int* __restrict__ bcnt, int E) {
    __shared__ int h[256];
    const int tid = threadIdx.x;
    h[tid] = 0;
    __syncthreads();
    const int base = blockIdx.x * 2048;
#pragma unroll
    for (int j = 0; j < 8; ++j) {
        int e = base + j * 256 + tid;
        if (e < E) atomicAdd(&h[dst[e] >> 9], 1);
    }
    __syncthreads();
    if (h[tid]) atomicAdd(&bcnt[tid], h[tid]);
}

// ---- scatter body: stage 2048 edges, bucket-group in LDS, flush runs ----
// mid entry: x = src | (dst&511)<<17 ; y = ew bits
struct ScatterSmem {
    int lcnt[256], loff[256], gbase[256], s[256], bb[256];
    int2 stage[2048];
    unsigned char sbk[2048];
};

__device__ __forceinline__ void scatter_body(char* smem, const int* __restrict__ src,
                                             const int* __restrict__ dst,
                                             const float* __restrict__ ew,
                                             const int* __restrict__ bcnt,
                                             int* __restrict__ cursor0,
                                             int2* __restrict__ mid, int E, int blk) {
    ScatterSmem& sm = *reinterpret_cast<ScatterSmem*>(smem);
    const int tid = threadIdx.x;
    const int base = blk * 2048;
    const int cnt = min(2048, E - base);
    // local exclusive scan of bcnt -> bb
    int bv = bcnt[tid];
    sm.s[tid] = bv;
    sm.lcnt[tid] = 0;
    __syncthreads();
    for (int off = 1; off < 256; off <<= 1) {
        int t = (tid >= off) ? sm.s[tid - off] : 0;
        __syncthreads();
        sm.s[tid] += t;
        __syncthreads();
    }
    sm.bb[tid] = sm.s[tid] - bv;
    __syncthreads();
    int myb[8], myr[8];
    int2 mye[8];
#pragma unroll
    for (int j = 0; j < 8; ++j) {
        int e = base + j * 256 + tid;
        myb[j] = -1;
        if (e < E) {
            int d = dst[e];
            int b = d >> 9;
            mye[j] = make_int2(src[e] | ((d & 511) << 17), __float_as_int(ew[e]));
            myr[j] = atomicAdd(&sm.lcnt[b], 1);
            myb[j] = b;
        }
    }
    __syncthreads();
    sm.s[tid] = sm.lcnt[tid];
    __syncthreads();
    for (int off = 1; off < 256; off <<= 1) {
        int t = (tid >= off) ? sm.s[tid - off] : 0;
        __syncthreads();
        sm.s[tid] += t;
        __syncthreads();
    }
    sm.loff[tid] = sm.s[tid] - sm.lcnt[tid];
    if (sm.lcnt[tid] > 0)
        sm.gbase[tid] = sm.bb[tid] + atomicAdd(&cursor0[tid], sm.lcnt[tid]);
    __syncthreads();
#pragma unroll
    for (int j = 0; j < 8; ++j) {
        if (myb[j] >= 0) {
            int pos = sm.loff[myb[j]] + myr[j];
            sm.stage[pos] = mye[j];
            sm.sbk[pos] = (unsigned char)myb[j];
        }
    }
    __syncthreads();
    for (int i = tid; i < cnt; i += 256) {
        int b = sm.sbk[i];
        mid[sm.gbase[b] + (i - sm.loff[b])] = sm.stage[i];
    }
}

// ---- gemm body: register-tiled, 2 rows x DOUT/16 cols per thread ----
// k-loop unroll bounded to 4: unbounded unroll spilled (VGPR=256, 474MB scratch, r6).
template <int DIN_, int DOUT_, bool RELU_IN>
__device__ __forceinline__ void gemm_body(char* smem, const float* __restrict__ X,
                                          const float* __restrict__ W,
                                          _Float16* __restrict__ H, int n, int row0) {
    constexpr int ROWS = 32;
    constexpr int CPT = DOUT_ / 16;
    constexpr int P4 = DIN_ / 4 + 1;
    float* sX = reinterpret_cast<float*>(smem);
    float* sWt = sX + ROWS * P4 * 4;
    const int tid = threadIdx.x;

    const float4* W4 = reinterpret_cast<const float4*>(W);
    for (int i = tid; i < DIN_ * DOUT_ / 4; i += 256) {
        float4 v = W4[i];
        int k = (4 * i) / DOUT_;
        int c = (4 * i) % DOUT_;
        sWt[(c + 0) * P4 * 4 + k] = v.x;
        sWt[(c + 1) * P4 * 4 + k] = v.y;
        sWt[(c + 2) * P4 * 4 + k] = v.z;
        sWt[(c + 3) * P4 * 4 + k] = v.w;
    }
    const float4* X4 = reinterpret_cast<const float4*>(X);
    constexpr int C4 = DIN_ / 4;
    for (int i = tid; i < ROWS * C4; i += 256) {
        int r = i / C4;
        int k4 = i % C4;
        float4 v = make_float4(0.f, 0.f, 0.f, 0.f);
        if (row0 + r < n) v = X4[(size_t)(row0 + r) * C4 + k4];
        if (RELU_IN) {
            v.x = fmaxf(v.x, 0.f); v.y = fmaxf(v.y, 0.f);
            v.z = fmaxf(v.z, 0.f); v.w = fmaxf(v.w, 0.f);
        }
        reinterpret_cast<float4*>(sX)[r * P4 + k4] = v;
    }
    __syncthreads();

    const int cg = tid & 15;
    const int r0 = (tid >> 4) * 2;
    const float4* sX4 = reinterpret_cast<const float4*>(sX);
    const float4* sWt4 = reinterpret_cast<const float4*>(sWt);
    float acc[2][CPT];
#pragma unroll
    for (int ri = 0; ri < 2; ++ri)
#pragma unroll
        for (int j = 0; j < CPT; ++j) acc[ri][j] = 0.0f;

#pragma unroll 4
    for (int k4 = 0; k4 < C4; ++k4) {
        float4 xa0 = sX4[(r0 + 0) * P4 + k4];
        float4 xa1 = sX4[(r0 + 1) * P4 + k4];
#pragma unroll
        for (int j = 0; j < CPT; ++j) {
            float4 wb = sWt4[(cg + j * 16) * P4 + k4];
            acc[0][j] = fmaf(xa0.x, wb.x, acc[0][j]);
            acc[0][j] = fmaf(xa0.y, wb.y, acc[0][j]);
            acc[0][j] = fmaf(xa0.z, wb.z, acc[0][j]);
            acc[0][j] = fmaf(xa0.w, wb.w, acc[0][j]);
            acc[1][j] = fmaf(xa1.x, wb.x, acc[1][j]);
            acc[1][j] = fmaf(xa1.y, wb.y, acc[1][j]);
            acc[1][j] = fmaf(xa1.z, wb.z, acc[1][j]);
            acc[1][j] = fmaf(xa1.w, wb.w, acc[1][j]);
        }
    }
#pragma unroll
    for (int ri = 0; ri < 2; ++ri) {
        int r = row0 + r0 + ri;
        if (r < n) {
#pragma unroll
            for (int j = 0; j < CPT; ++j)
                H[(size_t)r * DOUT_ + cg + j * 16] = (_Float16)acc[ri][j];
        }
    }
}

// fused: blocks [0,nsb) scatter, [nsb,..) gemm1 (independent work, overlapped)
__global__ __launch_bounds__(256, 4) void scatter_gemm1(
    const int* __restrict__ src, const int* __restrict__ dst, const float* __restrict__ ew,
    const int* __restrict__ bcnt, int* __restrict__ cursor0, int2* __restrict__ mid,
    int E, int nsb, const float* __restrict__ X, const float* __restrict__ W,
    _Float16* __restrict__ H, int n) {
    extern __shared__ char smem[];
    if ((int)blockIdx.x < nsb)
        scatter_body(smem, src, dst, ew, bcnt, cursor0, mid, E, blockIdx.x);
    else
        gemm_body<DIN1, DHID, false>(smem, X, W, H, n, (blockIdx.x - nsb) * 32);
}

// standalone gemm (layer 2)
template <int DIN_, int DOUT_, bool RELU_IN>
__global__ __launch_bounds__(256, 4) void gemm_kernel(const float* __restrict__ X,
                                                      const float* __restrict__ W,
                                                      _Float16* __restrict__ H, int n) {
    constexpr int P4 = DIN_ / 4 + 1;
    __shared__ char smem[(32 * P4 * 4 + DOUT_ * P4 * 4) * 4];
    gemm_body<DIN_, DOUT_, RELU_IN>(smem, X, W, H, n, blockIdx.x * 32);
}

// per-bucket: scan bcnt -> e0/e1; LDS count+deg; scan; degree-rank nodes
// (counting sort on min(cnt,63)) -> rank-indexed row_start/count/ord;
// dinv (orig-indexed); node-grouped ep within bucket (L2-local lines).
__global__ __launch_bounds__(256) void bucket_build(const int2* __restrict__ mid,
                                                    const int* __restrict__ bcnt,
                                                    int2* __restrict__ ep,
                                                    float* __restrict__ dinvg,
                                                    int* __restrict__ row_start,
                                                    int* __restrict__ countg,
                                                    int* __restrict__ ordg, int n) {
    __shared__ float sdeg[512];
    __shared__ int scnt[512], soff[512], scur[512], s2[256];
    __shared__ int dh[64], dcur[64], dbase[64];
    __shared__ int sE0, sE1;
    const int tid = threadIdx.x;
    const int b = blockIdx.x;
    const int n0 = b << 9;
    const int nr = min(512, n - n0);
    // scan bcnt for this bucket's edge span
    int bv = bcnt[tid];
    s2[tid] = bv;
    __syncthreads();
    for (int off = 1; off < 256; off <<= 1) {
        int t = (tid >= off) ? s2[tid - off] : 0;
        __syncthreads();
        s2[tid] += t;
        __syncthreads();
    }
    if (tid == b) { sE1 = s2[tid]; sE0 = s2[tid] - bv; }
    for (int i = tid; i < 512; i += 256) { sdeg[i] = 0.0f; scnt[i] = 0; }
    if (tid < 64) { dh[tid] = 0; dcur[tid] = 0; }
    __syncthreads();
    const int e0 = sE0, e1 = sE1;
    for (int i = e0 + tid; i < e1; i += 256) {
        int2 p = mid[i];
        int dl = (p.x >> 17) & 511;
        atomicAdd(&scnt[dl], 1);
        atomicAdd(&sdeg[dl], __int_as_float(p.y));
    }
    __syncthreads();
    int a0 = scnt[2 * tid], a1 = scnt[2 * tid + 1];
    s2[tid] = a0 + a1;
    __syncthreads();
    for (int off = 1; off < 256; off <<= 1) {
        int t = (tid >= off) ? s2[tid - off] : 0;
        __syncthreads();
        s2[tid] += t;
        __syncthreads();
    }
    int excl = s2[tid] - (a0 + a1);
    soff[2 * tid] = excl;
    soff[2 * tid + 1] = excl + a0;
    scur[2 * tid] = excl;
    scur[2 * tid + 1] = excl + a0;
    __syncthreads();
    // degree histogram -> counting-sort ranks (groups equal degrees -> wave uniformity)
    for (int i = tid; i < nr; i += 256) atomicAdd(&dh[min(scnt[i], 63)], 1);
    __syncthreads();
    if (tid == 0) {
        int run = 0;
        for (int d = 0; d < 64; ++d) { dbase[d] = run; run += dh[d]; }
    }
    __syncthreads();
    for (int i = tid; i < nr; i += 256) {
        int d = min(scnt[i], 63);
        int r = dbase[d] + atomicAdd(&dcur[d], 1);
        row_start[n0 + r] = e0 + soff[i];
        countg[n0 + r] = scnt[i];
        ordg[n0 + r] = n0 + i;
        dinvg[n0 + i] = rsqrtf(sdeg[i] + 1.0f);  // +1 self-loop
    }
    __syncthreads();
    for (int i = e0 + tid; i < e1; i += 256) {
        int2 p = mid[i];
        int dl = (p.x >> 17) & 511;
        int r = atomicAdd(&scur[dl], 1);
        ep[e0 + r] = make_int2(p.x & 0x1FFFF, p.y);
    }
}

// out[ord[ir]][c4] = b + dinv^2*h[orig][c4] + sum_edges dinv[src]*ew*dinv * h[src][c4]
template <int D>
__global__ __launch_bounds__(256) void aggregate_kernel(const int* __restrict__ row_start,
                                                        const int* __restrict__ count,
                                                        const int* __restrict__ ord,
                                                        const int2* __restrict__ ep,
                                                        const _Float16* __restrict__ h,
                                                        const float* __restrict__ dinv,
                                                        const float* __restrict__ b,
                                                        float* __restrict__ out, int n) {
    constexpr int C = D / 4;
    int gid = blockIdx.x * blockDim.x + threadIdx.x;
    if (gid >= n * C) return;
    int ir = gid / C;
    int c = gid % C;
    int orig = ord[ir];
    const half4_t* h4 = reinterpret_cast<const half4_t*>(h);
    float di = dinv[orig];
    float sl = di * di;
    half4_t hs = h4[(size_t)orig * C + c];
    float4 acc;
    acc.x = sl * (float)hs[0];
    acc.y = sl * (float)hs[1];
    acc.z = sl * (float)hs[2];
    acc.w = sl * (float)hs[3];
    int r0 = row_start[ir], r1 = r0 + count[ir];
    for (int k = r0; k < r1; ++k) {
        int2 p = ep[k];
        float nm = dinv[p.x] * __int_as_float(p.y) * di;
        half4_t hv = h4[(size_t)p.x * C + c];
        acc.x = fmaf(nm, (float)hv[0], acc.x);
        acc.y = fmaf(nm, (float)hv[1], acc.y);
        acc.z = fmaf(nm, (float)hv[2], acc.z);
        acc.w = fmaf(nm, (float)hv[3], acc.w);
    }
    float4 bv = reinterpret_cast<const float4*>(b)[c];
    acc.x += bv.x; acc.y += bv.y; acc.z += bv.z; acc.w += bv.w;
    reinterpret_cast<float4*>(out)[(size_t)orig * C + c] = acc;
}

extern "C" void kernel_launch(void* const* d_in, const int* in_sizes, int n_in,
                              void* d_out, int out_size, void* d_ws, size_t ws_size,
                              hipStream_t stream) {
    const float* x  = (const float*)d_in[0];
    const int*   ei = (const int*)d_in[1];
    const float* ew = (const float*)d_in[2];
    const float* W1 = (const float*)d_in[3];
    const float* b1 = (const float*)d_in[4];
    const float* W2 = (const float*)d_in[5];
    const float* b2 = (const float*)d_in[6];
    float* out = (float*)d_out;

    const int n = in_sizes[0] / DIN1;   // 100000
    const int E = in_sizes[1] / 2;      // 1600000
    const int* src = ei;
    const int* dst = ei + E;
    const int nb = (n + 511) >> 9;      // 196 buckets (<=256)

    // workspace layout (16B-aligned chunks)
    char* w = (char*)d_ws;
    int*   bcnt      = (int*)w;   w += 256 * 4;            // zeroed (with cursor0)
    int*   cursor0   = (int*)w;   w += 256 * 4;            // zeroed
    float* dinv      = (float*)w; w += (size_t)n * 4;
    int*   row_start = (int*)w;   w += (size_t)n * 4;
    int*   count     = (int*)w;   w += (size_t)n * 4;
    int*   ord       = (int*)w;   w += (size_t)n * 4;
    int2*  mid       = (int2*)w;  w += (size_t)E * 8;
    int2*  ep        = (int2*)w;  w += (size_t)E * 8;
    _Float16* h1     = (_Float16*)w; w += (size_t)n * DHID * 2;
    float* out1      = (float*)w; w += (size_t)n * DHID * 4;
    _Float16* h2     = (_Float16*)w;

    const int eblk = (E + 2047) / 2048;      // 782
    const int gblk = (n + 31) / 32;          // 3125
    const size_t fused_lds = (32 * (DIN1 / 4 + 1) * 4 + DHID * (DIN1 / 4 + 1) * 4) * 4;  // 42240

    hipMemsetAsync(bcnt, 0, 512 * 4, stream);  // bcnt + cursor0
    bin_count<<<eblk, 256, 0, stream>>>(dst, bcnt, E);
    scatter_gemm1<<<eblk + gblk, 256, fused_lds, stream>>>(src, dst, ew, bcnt, cursor0, mid,
                                                           E, eblk, x, W1, h1, n);
    bucket_build<<<nb, 256, 0, stream>>>(mid, bcnt, ep, dinv, row_start, count, ord, n);

    aggregate_kernel<DHID><<<(n * (DHID / 4) + 255) / 256, 256, 0, stream>>>(
        row_start, count, ord, ep, h1, dinv, b1, out1, n);

    gemm_kernel<DHID, DOUT, true><<<gblk, 256, 0, stream>>>(out1, W2, h2, n);
    aggregate_kernel<DOUT><<<(n * (DOUT / 4) + 255) / 256, 256, 0, stream>>>(
        row_start, count, ord, ep, h2, dinv, b2, out, n);
}